// Round 4
// baseline (293.499 us; speedup 1.0000x reference)
//
#include <hip/hip_runtime.h>

#define B 4
#define N 2048
#define V 12
#define C 50
#define P 16384      // 128*128 = 2^14
#define CP 64        // padded C stride in wfeat (256 B aligned per winner)

// ---------------------------------------------------------------------------
// Kernel 1: per-pixel argmax over C + masked atomicMax scatter of
// key = argmax*P + pixel into winner[b,v,n]. 4 pixels/thread via float4;
// every c-pass fully coalesced (157 MB stream).
// ---------------------------------------------------------------------------
__global__ __launch_bounds__(256) void k1_argmax_scatter(
    const float4* __restrict__ predv,    // (B*V, C, P/4)
    const int4*  __restrict__ p2pv,      // (B*V, P/4)
    const int*   __restrict__ parts_nb,  // (B,)
    int*         __restrict__ winner) {  // (B*V, N), pre-init -1
  const int PQ = P / 4;
  int t = blockIdx.x * 256 + threadIdx.x;
  if (t >= B * V * PQ) return;
  int q  = t % PQ;
  int bv = t / PQ;
  int b  = bv / V;

  size_t base = (size_t)bv * C * PQ + q;
  float4 x = predv[base];
  float m0 = x.x, m1 = x.y, m2 = x.z, m3 = x.w;
  int   a0 = 0,  a1 = 0,  a2 = 0,  a3 = 0;
  for (int c = 1; c < C; ++c) {
    float4 y = predv[base + (size_t)c * PQ];
    if (y.x > m0) { m0 = y.x; a0 = c; }
    if (y.y > m1) { m1 = y.y; a1 = c; }
    if (y.z > m2) { m2 = y.z; a2 = c; }
    if (y.w > m3) { m3 = y.w; a3 = c; }
  }

  int4 pt = p2pv[(size_t)bv * PQ + q];
  int pn = parts_nb[b];
  int p0 = q * 4;
  int* wbase = winner + bv * N;
  if (pt.x != -1 && a0 >= 1 && a0 <= pn) atomicMax(wbase + pt.x, a0 * P + p0);
  if (pt.y != -1 && a1 >= 1 && a1 <= pn) atomicMax(wbase + pt.y, a1 * P + p0 + 1);
  if (pt.z != -1 && a2 >= 1 && a2 <= pn) atomicMax(wbase + pt.z, a2 * P + p0 + 2);
  if (pt.w != -1 && a3 >= 1 && a3 <= pn) atomicMax(wbase + pt.w, a3 * P + p0 + 3);
}

// ---------------------------------------------------------------------------
// Kernel 2: second COALESCED streaming pass (same loop shape as k1).
// Each thread owns 4 pixels; determines once which (if any) are winner
// pixels (winner key encodes the winning pixel uniquely). On every
// c-iteration it loads float4 unconditionally (coalesced) and
// predicate-stores exp(logit) into wfeat[bvn][c], accumulating sexp.
// Only the unique winner pixel for a given bvn ever stores -> no races.
// ---------------------------------------------------------------------------
__global__ __launch_bounds__(256) void k2_extract(
    const float4* __restrict__ predv,   // (B*V, C, P/4)
    const int4*  __restrict__ p2pv,     // (B*V, P/4)
    const int*   __restrict__ winner,   // (B*V, N)
    float*       __restrict__ wfeat,    // (B*V*N, CP) unnormalized exp
    float*       __restrict__ wsum) {   // (B*V*N,)    sum of exp
  const int PQ = P / 4;
  int t = blockIdx.x * 256 + threadIdx.x;
  if (t >= B * V * PQ) return;
  int q  = t % PQ;
  int bv = t / PQ;

  int4 pt = p2pv[(size_t)bv * PQ + q];
  int p0 = q * 4;
  const int* wb = winner + bv * N;

  bool w0 = false, w1 = false, w2 = false, w3 = false;
  int n0 = 0, n1 = 0, n2 = 0, n3 = 0;
  if (pt.x != -1) { int k = wb[pt.x]; w0 = (k >= 0) && ((k & (P-1)) == p0    ); n0 = bv * N + pt.x; }
  if (pt.y != -1) { int k = wb[pt.y]; w1 = (k >= 0) && ((k & (P-1)) == p0 + 1); n1 = bv * N + pt.y; }
  if (pt.z != -1) { int k = wb[pt.z]; w2 = (k >= 0) && ((k & (P-1)) == p0 + 2); n2 = bv * N + pt.z; }
  if (pt.w != -1) { int k = wb[pt.w]; w3 = (k >= 0) && ((k & (P-1)) == p0 + 3); n3 = bv * N + pt.w; }

  float* d0 = wfeat + (size_t)n0 * CP;
  float* d1 = wfeat + (size_t)n1 * CP;
  float* d2 = wfeat + (size_t)n2 * CP;
  float* d3 = wfeat + (size_t)n3 * CP;

  size_t base = (size_t)bv * C * PQ + q;
  float s0 = 0.f, s1 = 0.f, s2 = 0.f, s3 = 0.f;
  for (int c = 0; c < C; ++c) {
    float4 y = predv[base + (size_t)c * PQ];     // unconditional -> coalesced
    float e0 = __expf(y.x), e1 = __expf(y.y), e2 = __expf(y.z), e3 = __expf(y.w);
    if (w0) { d0[c] = e0; s0 += e0; }
    if (w1) { d1[c] = e1; s1 += e1; }
    if (w2) { d2[c] = e2; s2 += e2; }
    if (w3) { d3[c] = e3; s3 += e3; }
  }
  if (w0) wsum[n0] = s0;
  if (w1) wsum[n1] = s1;
  if (w2) wsum[n2] = s2;
  if (w3) wsum[n3] = s3;
}

// ---------------------------------------------------------------------------
// Kernel 3: one wave per (b,n). Lanes 0..49 read wfeat coalesced (4 aligned
// lines per (v,n)); acc += e_c * (vw_v / sexp); divide by valid-view count.
// ---------------------------------------------------------------------------
__global__ __launch_bounds__(256) void k3_reduce(
    const int*   __restrict__ winner,   // (B*V, N)
    const float* __restrict__ wfeat,    // (B*V*N, CP)
    const float* __restrict__ wsum,     // (B*V*N,)
    const float* __restrict__ vw,       // (B*V,)
    float*       __restrict__ out) {    // (B, C, N)
  int wid  = blockIdx.x * 4 + (threadIdx.x >> 6);
  int lane = threadIdx.x & 63;
  int b = wid >> 11;                    // N = 2048
  int n = wid & (N - 1);

  float acc = 0.f;
  int cnt = 0;
  #pragma unroll
  for (int v = 0; v < V; ++v) {
    int bvn = (b * V + v) * N + n;
    bool valid = winner[bvn] >= 0;
    float e = (valid && lane < C) ? wfeat[(size_t)bvn * CP + lane] : 0.f;
    float f = valid ? (vw[b * V + v] / wsum[bvn]) : 0.f;
    cnt += valid ? 1 : 0;
    acc += e * f;
  }
  if (lane < C)
    out[((size_t)b * C + lane) * N + n] = acc / (float)(cnt > 0 ? cnt : 1);
}

extern "C" void kernel_launch(void* const* d_in, const int* in_sizes, int n_in,
                              void* d_out, int out_size, void* d_ws, size_t ws_size,
                              hipStream_t stream) {
  const float* pred  = (const float*)d_in[1];
  const int*   p2p   = (const int*)d_in[2];
  const float* vw    = (const float*)d_in[3];
  const int*   parts = (const int*)d_in[4];
  float* out = (float*)d_out;

  char* ws = (char*)d_ws;
  int*   winner = (int*)ws;                         ws += (size_t)B * V * N * sizeof(int);   // 384 KiB
  float* wsum   = (float*)ws;                       ws += (size_t)B * V * N * sizeof(float); // 384 KiB
  float* wfeat  = (float*)ws;                                                                // 24 MiB

  hipMemsetAsync(winner, 0xFF, (size_t)B * V * N * sizeof(int), stream);

  int nthreads = B * V * (P / 4);                   // 196608
  k1_argmax_scatter<<<(nthreads + 255) / 256, 256, 0, stream>>>(
      (const float4*)pred, (const int4*)p2p, parts, winner);

  k2_extract<<<(nthreads + 255) / 256, 256, 0, stream>>>(
      (const float4*)pred, (const int4*)p2p, winner, wfeat, wsum);

  k3_reduce<<<(B * N) / 4, 256, 0, stream>>>(winner, wfeat, wsum, vw, out);
}